// Round 1
// baseline (329.166 us; speedup 1.0000x reference)
//
#include <hip/hip_runtime.h>

#define W_IN 80
#define H_IN 80
#define HW_IN (W_IN * H_IN)      // 6400
#define C_IN 256
#define NG 4                     // groups
#define NOFF 32                  // 2 * NG * SCALE^2
#define W_OUT 160
#define H_OUT 160
#define HW_OUT (W_OUT * H_OUT)   // 25600

// ---------------------------------------------------------------------------
// Kernel A: 1x1 conv (256 -> 32) + coordinate precompute.
// One thread per source pixel (b, y, x). Weights staged in LDS as [c][o]
// (wave-uniform ds_read_b128 -> broadcast). Emits (ix, iy) float2 per
// (b, k, y, x), k in [0,16), clipped to the border — everything downstream
// of the conv collapses algebraically to:
//   ix = clip(x + 0.25*off[k]    + h[j], 0, W-1),  h = {-0.25, +0.25}
//   iy = clip(y + 0.25*off[16+k] + h[i], 0, H-1),  k = gi*4 + i*2 + j
// ---------------------------------------------------------------------------
__global__ __launch_bounds__(256) void conv_coords_kernel(
    const float* __restrict__ x, const float* __restrict__ w,
    const float* __restrict__ bias, float2* __restrict__ coords) {
  __shared__ float ws[C_IN * NOFF];  // 32 KB, layout [c][o]
  const int t = threadIdx.x;
#pragma unroll
  for (int i = 0; i < (C_IN * NOFF) / 256; ++i) {
    int idx = i * 256 + t;
    int c = idx >> 5, o = idx & 31;
    ws[idx] = w[o * C_IN + c];  // transpose (o,c) -> (c,o)
  }
  __syncthreads();

  const int p = blockIdx.x * 256 + t;       // [0, 51200)
  const int b = p / HW_IN;
  const int yx = p - b * HW_IN;
  const float* xp = x + (size_t)b * C_IN * HW_IN + yx;

  float acc[NOFF];
#pragma unroll
  for (int o = 0; o < NOFF; ++o) acc[o] = bias[o];

#pragma unroll 4
  for (int c = 0; c < C_IN; ++c) {
    float v = xp[(size_t)c * HW_IN];  // coalesced across lanes (consecutive yx)
    const float4* w4 = reinterpret_cast<const float4*>(&ws[c * NOFF]);
#pragma unroll
    for (int o4 = 0; o4 < NOFF / 4; ++o4) {
      float4 wv = w4[o4];
      acc[o4 * 4 + 0] = fmaf(v, wv.x, acc[o4 * 4 + 0]);
      acc[o4 * 4 + 1] = fmaf(v, wv.y, acc[o4 * 4 + 1]);
      acc[o4 * 4 + 2] = fmaf(v, wv.z, acc[o4 * 4 + 2]);
      acc[o4 * 4 + 3] = fmaf(v, wv.w, acc[o4 * 4 + 3]);
    }
  }

  const int y = yx / W_IN;
  const int xc = yx - y * W_IN;
#pragma unroll
  for (int k = 0; k < 16; ++k) {
    float hx = (k & 1) ? 0.25f : -0.25f;  // h[j], j = k&1
    float hy = (k & 2) ? 0.25f : -0.25f;  // h[i], i = (k>>1)&1
    float ix = fminf(fmaxf((float)xc + fmaf(0.25f, acc[k], hx), 0.0f),
                     (float)(W_IN - 1));
    float iy = fminf(fmaxf((float)y + fmaf(0.25f, acc[16 + k], hy), 0.0f),
                     (float)(H_IN - 1));
    coords[(size_t)(b * 16 + k) * HW_IN + yx] = make_float2(ix, iy);  // coalesced
  }
}

// ---------------------------------------------------------------------------
// Kernel B: bilinear border-clamped gather. One thread per output spatial
// position (b, gi, oy, ox); inner loop over the 64 channels of the group.
// Bilinear weights and the 4 flat gather offsets are computed once per
// thread; per channel: 4 near-coalesced gathers + 1 coalesced store.
// ---------------------------------------------------------------------------
__global__ __launch_bounds__(256) void sample_kernel(
    const float* __restrict__ x, const float2* __restrict__ coords,
    float* __restrict__ out) {
  const int idx = blockIdx.x * 256 + threadIdx.x;  // [0, 819200)
  const int ox = idx % W_OUT;
  const int r1d = idx / W_OUT;
  const int oy = r1d % H_OUT;
  const int r2d = r1d / H_OUT;
  const int gi = r2d & 3;
  const int b = r2d >> 2;

  const int xs = ox >> 1, j = ox & 1;
  const int ys = oy >> 1, i = oy & 1;
  const int k = gi * 4 + i * 2 + j;

  const float2 c2 = coords[(size_t)(b * 16 + k) * HW_IN + ys * W_IN + xs];
  const float fx0 = floorf(c2.x), fy0 = floorf(c2.y);
  const int x0 = (int)fx0, y0 = (int)fy0;
  const float wx = c2.x - fx0, wy = c2.y - fy0;
  const int x1 = min(x0 + 1, W_IN - 1), y1 = min(y0 + 1, H_IN - 1);

  const float w00 = (1.0f - wy) * (1.0f - wx);
  const float w01 = (1.0f - wy) * wx;
  const float w10 = wy * (1.0f - wx);
  const float w11 = wy * wx;

  const int o00 = y0 * W_IN + x0;
  const int o01 = y0 * W_IN + x1;
  const int o10 = y1 * W_IN + x0;
  const int o11 = y1 * W_IN + x1;

  const float* xp = x + (size_t)(b * C_IN + gi * 64) * HW_IN;
  float* op = out + (size_t)(b * C_IN + gi * 64) * HW_OUT + oy * W_OUT + ox;

#pragma unroll 4
  for (int c = 0; c < 64; ++c) {
    const float* pc = xp + c * HW_IN;
    float v = pc[o00] * w00 + pc[o01] * w01 + pc[o10] * w10 + pc[o11] * w11;
    op[c * HW_OUT] = v;  // coalesced across lanes for each c
  }
}

extern "C" void kernel_launch(void* const* d_in, const int* in_sizes, int n_in,
                              void* d_out, int out_size, void* d_ws,
                              size_t ws_size, hipStream_t stream) {
  const float* x = (const float*)d_in[0];      // (8, 256, 80, 80)
  const float* w_off = (const float*)d_in[1];  // (32, 256, 1, 1)
  const float* b_off = (const float*)d_in[2];  // (32,)
  float* out = (float*)d_out;                  // (8, 256, 160, 160)
  float2* coords = (float2*)d_ws;              // 819200 float2 = 6.55 MB

  // Kernel A: 8*80*80 = 51200 pixels, 256/thread-block -> 200 blocks
  conv_coords_kernel<<<200, 256, 0, stream>>>(x, w_off, b_off, coords);
  // Kernel B: 8*4*160*160 = 819200 positions -> 3200 blocks
  sample_kernel<<<3200, 256, 0, stream>>>(x, coords, out);
}

// Round 3
// 299.417 us; speedup vs baseline: 1.0994x; 1.0994x over previous
//
#include <hip/hip_runtime.h>

#define W_IN 80
#define H_IN 80
#define HW_IN 6400
#define C_IN 256
#define NOFF 32
#define W_OUT 160
#define H_OUT 160
#define HW_OUT 25600

// 8-byte vector load that is legal at 4-byte alignment (x0 parity is random).
// gfx950 supports unaligned global access; worst case the compiler splits it
// into 2 dword loads and we are no worse than the scalar version.
typedef float f2u __attribute__((ext_vector_type(2), aligned(4)));

// ---------------------------------------------------------------------------
// Kernel A: 1x1 conv (256 -> 32) + coordinate precompute.
// Block = 256 threads = 4 waves, handles 64 consecutive source pixels.
// Wave w accumulates channels [64w, 64w+64) for all 64 pixels (lane = pixel),
// then a 4-step LDS reduction combines the partials; finally the block emits
// the 64px x 16k (ix,iy) pairs, coalesced.
//   ix = clip(xs + 0.25*off[k]    + h[k&1],      0, 79)
//   iy = clip(ys + 0.25*off[16+k] + h[(k>>1)&1], 0, 79),  h = {-0.25,+0.25}
// ---------------------------------------------------------------------------
__global__ __launch_bounds__(256) void conv_coords_kernel(
    const float* __restrict__ x, const float* __restrict__ w,
    const float* __restrict__ bias, float2* __restrict__ coords) {
  __shared__ float ws[C_IN * NOFF];       // 32 KB, [c][o]
  __shared__ float offb[64][NOFF + 1];    // +1 pad: conflict-free lane-major access
  const int t = threadIdx.x;
  const int lane = t & 63;
  const int wv = t >> 6;

#pragma unroll
  for (int i = 0; i < (C_IN * NOFF) / 256; ++i) {
    int idx = i * 256 + t;
    int c = idx >> 5, o = idx & 31;
    ws[idx] = w[o * C_IN + c];  // transpose (o,c) -> (c,o); 32KB, L2-resident
  }
  __syncthreads();

  const int pix0 = blockIdx.x * 64;   // 64 pixels / block, 100 blocks per batch
  const int b = blockIdx.x / 100;
  const int yx0 = pix0 - b * HW_IN;
  const int yx = yx0 + lane;

  const float* xp = x + ((size_t)b * C_IN + wv * 64) * HW_IN + yx;

  float acc[NOFF];
#pragma unroll
  for (int o = 0; o < NOFF; ++o) acc[o] = 0.0f;

#pragma unroll 4
  for (int cc = 0; cc < 64; ++cc) {
    float v = xp[(size_t)cc * HW_IN];  // coalesced: lanes = consecutive yx
    const float4* w4 = reinterpret_cast<const float4*>(&ws[(wv * 64 + cc) * NOFF]);
#pragma unroll
    for (int o4 = 0; o4 < NOFF / 4; ++o4) {
      float4 wvv = w4[o4];  // wave-uniform address -> LDS broadcast
      acc[o4 * 4 + 0] = fmaf(v, wvv.x, acc[o4 * 4 + 0]);
      acc[o4 * 4 + 1] = fmaf(v, wvv.y, acc[o4 * 4 + 1]);
      acc[o4 * 4 + 2] = fmaf(v, wvv.z, acc[o4 * 4 + 2]);
      acc[o4 * 4 + 3] = fmaf(v, wvv.w, acc[o4 * 4 + 3]);
    }
  }

  // Cross-wave reduction: offb[px][o] = bias[o] + sum_w acc_w[o]
  __syncthreads();
  if (wv == 0) {
#pragma unroll
    for (int o = 0; o < NOFF; ++o) offb[lane][o] = acc[o] + bias[o];
  }
  __syncthreads();
  if (wv == 1) {
#pragma unroll
    for (int o = 0; o < NOFF; ++o) offb[lane][o] += acc[o];
  }
  __syncthreads();
  if (wv == 2) {
#pragma unroll
    for (int o = 0; o < NOFF; ++o) offb[lane][o] += acc[o];
  }
  __syncthreads();
  if (wv == 3) {
#pragma unroll
    for (int o = 0; o < NOFF; ++o) offb[lane][o] += acc[o];
  }
  __syncthreads();

  // Emit coords: 64 px * 16 k = 1024 float2. r-loop mapping keeps stores
  // coalesced: lanes = consecutive px, k wave-uniform.
#pragma unroll
  for (int r = 0; r < 4; ++r) {
    int id = r * 256 + t;       // 0..1023
    int k = id >> 6;            // wave-uniform
    int px = id & 63;
    float offx = offb[px][k];
    float offy = offb[px][16 + k];
    int yxp = yx0 + px;
    int y = yxp / W_IN;
    int xc = yxp - y * W_IN;
    float hx = (k & 1) ? 0.25f : -0.25f;
    float hy = (k & 2) ? 0.25f : -0.25f;
    float ix = fminf(fmaxf((float)xc + fmaf(0.25f, offx, hx), 0.0f),
                     (float)(W_IN - 1));
    float iy = fminf(fmaxf((float)y + fmaf(0.25f, offy, hy), 0.0f),
                     (float)(H_IN - 1));
    coords[((size_t)b * 16 + k) * HW_IN + yxp] = make_float2(ix, iy);
  }
}

// ---------------------------------------------------------------------------
// Kernel B: bilinear border-clamped gather. One thread per output spatial
// position (b, gi, oy, ox); inner loop over the group's 64 channels.
// (v00,v01) and (v10,v11) are memory-adjacent -> one 8B load each.
// x0==79 implies wx==0 exactly (ix is clipped to 79.0), so clamping the load
// column to 78 and selecting .y for v00/v10 is exact and never reads OOB.
// ---------------------------------------------------------------------------
__global__ __launch_bounds__(256) void sample_kernel(
    const float* __restrict__ x, const float2* __restrict__ coords,
    float* __restrict__ out) {
  const int idx = blockIdx.x * 256 + threadIdx.x;  // [0, 819200)
  const int ox = idx % W_OUT;
  const int r1 = idx / W_OUT;
  const int oy = r1 % H_OUT;
  const int r2 = r1 / H_OUT;
  const int gi = r2 & 3;
  const int b = r2 >> 2;

  const int xs = ox >> 1, j = ox & 1;
  const int ys = oy >> 1, i = oy & 1;
  const int k = gi * 4 + i * 2 + j;

  const float2 c2 = coords[((size_t)b * 16 + k) * HW_IN + ys * W_IN + xs];
  const float fx0 = floorf(c2.x), fy0 = floorf(c2.y);
  const int x0 = (int)fx0, y0 = (int)fy0;
  const float wx = c2.x - fx0, wy = c2.y - fy0;
  const int y1 = min(y0 + 1, H_IN - 1);
  const int xl = min(x0, W_IN - 2);
  const bool xe = (x0 == W_IN - 1);

  const int o0 = y0 * W_IN + xl;
  const int o1 = y1 * W_IN + xl;

  const float* xp = x + ((size_t)b * C_IN + gi * 64) * HW_IN;
  float* op = out + ((size_t)b * C_IN + gi * 64) * HW_OUT + oy * W_OUT + ox;

#pragma unroll 4
  for (int c = 0; c < 64; ++c) {
    const float* pc = xp + c * HW_IN;
    f2u a = *reinterpret_cast<const f2u*>(pc + o0);
    f2u bt = *reinterpret_cast<const f2u*>(pc + o1);
    float v00 = xe ? a.y : a.x;
    float v10 = xe ? bt.y : bt.x;
    float h0 = fmaf(wx, a.y - v00, v00);
    float h1 = fmaf(wx, bt.y - v10, v10);
    float v = fmaf(wy, h1 - h0, h0);
    __builtin_nontemporal_store(v, &op[(size_t)c * HW_OUT]);  // write-once stream
  }
}

extern "C" void kernel_launch(void* const* d_in, const int* in_sizes, int n_in,
                              void* d_out, int out_size, void* d_ws,
                              size_t ws_size, hipStream_t stream) {
  const float* x = (const float*)d_in[0];      // (8, 256, 80, 80)
  const float* w_off = (const float*)d_in[1];  // (32, 256, 1, 1)
  const float* b_off = (const float*)d_in[2];  // (32,)
  float* out = (float*)d_out;                  // (8, 256, 160, 160)
  float2* coords = (float2*)d_ws;              // 819200 float2 = 6.55 MB

  // Kernel A: 51200 pixels / 64 per block -> 800 blocks (3.1 blocks/CU)
  conv_coords_kernel<<<800, 256, 0, stream>>>(x, w_off, b_off, coords);
  // Kernel B: 819200 positions -> 3200 blocks
  sample_kernel<<<3200, 256, 0, stream>>>(x, coords, out);
}